// Round 4
// baseline (381.256 us; speedup 1.0000x reference)
//
#include <hip/hip_runtime.h>

// LayerHypercube: out[b, f*1024+o] = sum_j x[b, o^(1<<j)] * w[f,j,o] + bias[f,o] + x[b,o]
// B=2048, F=16, O=I=1024, BITS=10. fm analytic (o^(1<<j)) -- not read.
//
// R3 post-mortem: kernel ~45 us vs 21 us HBM-write floor (after ~105 us fixed
// harness fills). VALU floor is only ~4.7 us (4 SIMDs/CU). Residual theory:
// store path (256B scattered store_dword) + per-output instruction overhead.
//
// R4: 4 outputs per lane (float4). Wave owns a 256-o quarter (lane l <-> o =
// q*256 + 4l..4l+3) and 2 feature maps (88 weight regs). Gathers:
//   j=0 (^1), j=1 (^2): register swizzles of the local float4 (free)
//   j=2..7 (^4..^128): ds_read_b128 at lane^(1,2,4,8,16,32) -- bank-perm, free
//   j=8 (^256), j=9 (^512): ds_read_b128 from quarter q^1 / q^2 at same lane
// Stores: global_store_dwordx4, 1 KB contiguous per wave-inst (4x fewer insts).
// Block = 256 thr = 4 waves = f-pairs {f0..f0+7} for one quarter; LDS stages
// quarters {q, q^1, q^2} x 16 rows = 48 KB (3 blocks/CU).

#define BTILE 16

__global__ __launch_bounds__(256, 3) void hypercube_kernel(
    const float* __restrict__ x,      // [2048][1024]
    const float* __restrict__ w,      // [16][10][1024]
    const float* __restrict__ bias,   // [16][1024]
    float* __restrict__ out)          // [2048][16*1024]
{
    __shared__ float4 xs4[BTILE * 3 * 64];   // 48 KB: [row][slot][lane]

    const int tid   = threadIdx.x;
    const int lane  = tid & 63;
    const int wave  = tid >> 6;            // 0..3
    const int q     = blockIdx.x & 3;      // o-quarter (256 outputs)
    const int fh    = (blockIdx.x >> 2) & 1;
    const int btile = blockIdx.x >> 3;
    const int b0    = btile * BTILE;
    const int f0    = fh * 8 + wave * 2;   // this wave's f-pair
    const int obase = q * 256 + lane * 4;

    // ---- Stage quarters {q, q^1, q^2} for BTILE rows: 3072 float4, 12/thread ----
    #pragma unroll
    for (int it = 0; it < 12; ++it) {
        const int i    = it * 256 + tid;       // float4 index in xs4
        const int row  = i / 192;              // 192 float4 per row
        const int rem  = i - row * 192;
        const int slot = rem >> 6;             // 0..2 -> quarter q^slot
        const int l4   = rem & 63;
        xs4[i] = *(const float4*)&x[(size_t)(b0 + row) * 1024 + (q ^ slot) * 256 + l4 * 4];
    }

    // ---- Weights for 2 f's at this lane's 4 o's (issued during staging) ----
    float4 wr[2][10], br[2];
    #pragma unroll
    for (int ff = 0; ff < 2; ++ff) {
        const int f = f0 + ff;
        #pragma unroll
        for (int j = 0; j < 10; ++j)
            wr[ff][j] = *(const float4*)&w[(size_t)(f * 10 + j) * 1024 + obase];
        br[ff] = *(const float4*)&bias[(size_t)f * 1024 + obase];
    }

    __syncthreads();

    // ---- Pure LDS + FMA + dwordx4-store loop ----
    #pragma unroll 1
    for (int row = 0; row < BTILE; ++row) {
        const float4* __restrict__ xr = &xs4[row * 192];
        const float4 v  = xr[lane];         // o ^ 0 (local)
        const float4 g2 = xr[lane ^ 1];     // o ^ 4
        const float4 g3 = xr[lane ^ 2];     // o ^ 8
        const float4 g4 = xr[lane ^ 4];     // o ^ 16
        const float4 g5 = xr[lane ^ 8];     // o ^ 32
        const float4 g6 = xr[lane ^ 16];    // o ^ 64
        const float4 g7 = xr[lane ^ 32];    // o ^ 128
        const float4 g8 = xr[64  + lane];   // o ^ 256 (quarter q^1)
        const float4 g9 = xr[128 + lane];   // o ^ 512 (quarter q^2)
        const float4 g0 = make_float4(v.y, v.x, v.w, v.z);   // o ^ 1
        const float4 g1 = make_float4(v.z, v.w, v.x, v.y);   // o ^ 2

        float* __restrict__ ob = out + (size_t)(b0 + row) * 16384 + obase;
        #pragma unroll
        for (int ff = 0; ff < 2; ++ff) {
            float4 a;
            a.x = br[ff].x + v.x;            // bias + tiled-x term
            a.y = br[ff].y + v.y;
            a.z = br[ff].z + v.z;
            a.w = br[ff].w + v.w;
            #define FMA4(G, J) \
                a.x = fmaf((G).x, wr[ff][J].x, a.x); \
                a.y = fmaf((G).y, wr[ff][J].y, a.y); \
                a.z = fmaf((G).z, wr[ff][J].z, a.z); \
                a.w = fmaf((G).w, wr[ff][J].w, a.w);
            FMA4(g0, 0) FMA4(g1, 1) FMA4(g2, 2) FMA4(g3, 3) FMA4(g4, 4)
            FMA4(g5, 5) FMA4(g6, 6) FMA4(g7, 7) FMA4(g8, 8) FMA4(g9, 9)
            #undef FMA4
            *(float4*)&ob[(size_t)(f0 + ff) * 1024] = a;   // 1 KB contiguous store
        }
    }
}

extern "C" void kernel_launch(void* const* d_in, const int* in_sizes, int n_in,
                              void* d_out, int out_size, void* d_ws, size_t ws_size,
                              hipStream_t stream) {
    const float* x    = (const float*)d_in[0];
    const float* w    = (const float*)d_in[1];
    const float* bias = (const float*)d_in[2];
    // d_in[3] = fm (int32) -- analytic, unused.
    float* out = (float*)d_out;

    dim3 grid(4 * 2 * (2048 / BTILE));   // quarters x f-halves x btiles = 1024
    dim3 block(256);
    hypercube_kernel<<<grid, block, 0, stream>>>(x, w, bias, out);
}

// Round 5
// 193.236 us; speedup vs baseline: 1.9730x; 1.9730x over previous
//
#include <hip/hip_runtime.h>

// LayerHypercube: out[b, f*1024+o] = sum_j x[b, o^(1<<j)] * w[f,j,o] + bias[f,o] + x[b,o]
// B=2048, F=16, O=I=1024, BITS=10. fm analytic (o^(1<<j)) -- not read.
//
// R4 post-mortem: __launch_bounds__(256,3) capped VGPRs; compiler allocated 84
// (< the 88 weight floats needed) and rematerialized weight loads inside the
// row loop -> FETCH 372 MB, WRITE 231 MB (scratch), 281 us latency-bound.
// R5 = R4 with __launch_bounds__(256,2): 256-VGPR budget so weights stay
// resident. Occupancy is LDS-limited at 3 blocks/CU (12 waves/CU) either way.
//
// Structure: wave owns a 256-o quarter (lane <-> 4 consecutive o) and 2 f's.
//   j=0 (^1), j=1 (^2): register swizzles of the local float4 (free)
//   j=2..7 (^4..^128): ds_read_b128 at lane^(1..32) -- bank-permutation
//   j=8 (^256), j=9 (^512): ds_read_b128 from staged quarter q^1 / q^2
// Stores: global_store_dwordx4, 1 KB contiguous per wave-inst.
// Pipe floors/CU: LDS ~14 us, VALU ~5 us, HBM writes ~21 us (the target).

#define BTILE 16

__global__ __launch_bounds__(256, 2) void hypercube_kernel(
    const float* __restrict__ x,      // [2048][1024]
    const float* __restrict__ w,      // [16][10][1024]
    const float* __restrict__ bias,   // [16][1024]
    float* __restrict__ out)          // [2048][16*1024]
{
    __shared__ float4 xs4[BTILE * 3 * 64];   // 48 KB: [row][slot][lane]

    const int tid   = threadIdx.x;
    const int lane  = tid & 63;
    const int wave  = tid >> 6;            // 0..3
    const int q     = blockIdx.x & 3;      // o-quarter (256 outputs)
    const int fh    = (blockIdx.x >> 2) & 1;
    const int btile = blockIdx.x >> 3;
    const int b0    = btile * BTILE;
    const int f0    = fh * 8 + wave * 2;   // this wave's f-pair
    const int obase = q * 256 + lane * 4;

    // ---- Stage quarters {q, q^1, q^2} for BTILE rows: 3072 float4, 12/thread ----
    #pragma unroll
    for (int it = 0; it < 12; ++it) {
        const int i    = it * 256 + tid;       // float4 index in xs4
        const int row  = i / 192;              // 192 float4 per row
        const int rem  = i - row * 192;
        const int slot = rem >> 6;             // 0..2 -> quarter q^slot
        const int l4   = rem & 63;
        xs4[i] = *(const float4*)&x[(size_t)(b0 + row) * 1024 + (q ^ slot) * 256 + l4 * 4];
    }

    // ---- Weights for 2 f's at this lane's 4 o's (latency overlaps staging) ----
    float4 wr[2][10], br[2];
    #pragma unroll
    for (int ff = 0; ff < 2; ++ff) {
        const int f = f0 + ff;
        #pragma unroll
        for (int j = 0; j < 10; ++j)
            wr[ff][j] = *(const float4*)&w[(size_t)(f * 10 + j) * 1024 + obase];
        br[ff] = *(const float4*)&bias[(size_t)f * 1024 + obase];
    }

    __syncthreads();

    // ---- Pure LDS + FMA + dwordx4-store loop ----
    #pragma unroll 1
    for (int row = 0; row < BTILE; ++row) {
        const float4* __restrict__ xr = &xs4[row * 192];
        const float4 v  = xr[lane];         // o ^ 0 (local)
        const float4 g2 = xr[lane ^ 1];     // o ^ 4
        const float4 g3 = xr[lane ^ 2];     // o ^ 8
        const float4 g4 = xr[lane ^ 4];     // o ^ 16
        const float4 g5 = xr[lane ^ 8];     // o ^ 32
        const float4 g6 = xr[lane ^ 16];    // o ^ 64
        const float4 g7 = xr[lane ^ 32];    // o ^ 128
        const float4 g8 = xr[64  + lane];   // o ^ 256 (quarter q^1)
        const float4 g9 = xr[128 + lane];   // o ^ 512 (quarter q^2)
        const float4 g0 = make_float4(v.y, v.x, v.w, v.z);   // o ^ 1
        const float4 g1 = make_float4(v.z, v.w, v.x, v.y);   // o ^ 2

        float* __restrict__ ob = out + (size_t)(b0 + row) * 16384 + obase;
        #pragma unroll
        for (int ff = 0; ff < 2; ++ff) {
            float4 a;
            a.x = br[ff].x + v.x;            // bias + tiled-x term
            a.y = br[ff].y + v.y;
            a.z = br[ff].z + v.z;
            a.w = br[ff].w + v.w;
            #define FMA4(G, J) \
                a.x = fmaf((G).x, wr[ff][J].x, a.x); \
                a.y = fmaf((G).y, wr[ff][J].y, a.y); \
                a.z = fmaf((G).z, wr[ff][J].z, a.z); \
                a.w = fmaf((G).w, wr[ff][J].w, a.w);
            FMA4(g0, 0) FMA4(g1, 1) FMA4(g2, 2) FMA4(g3, 3) FMA4(g4, 4)
            FMA4(g5, 5) FMA4(g6, 6) FMA4(g7, 7) FMA4(g8, 8) FMA4(g9, 9)
            #undef FMA4
            *(float4*)&ob[(size_t)(f0 + ff) * 1024] = a;   // 1 KB contiguous store
        }
    }
}

extern "C" void kernel_launch(void* const* d_in, const int* in_sizes, int n_in,
                              void* d_out, int out_size, void* d_ws, size_t ws_size,
                              hipStream_t stream) {
    const float* x    = (const float*)d_in[0];
    const float* w    = (const float*)d_in[1];
    const float* bias = (const float*)d_in[2];
    // d_in[3] = fm (int32) -- analytic, unused.
    float* out = (float*)d_out;

    dim3 grid(4 * 2 * (2048 / BTILE));   // quarters x f-halves x btiles = 1024
    dim3 block(256);
    hypercube_kernel<<<grid, block, 0, stream>>>(x, w, bias, out);
}